// Round 1
// baseline (518.834 us; speedup 1.0000x reference)
//
#include <hip/hip_runtime.h>
#include <math.h>

#define NBATCH 64
#define Q      1000
#define C      1203
#define QC     1203000      // Q*C
#define QC4    300750       // QC/4
#define K      100
#define NBINS  2048         // top 11 bits of monotonic key (fallback path)
#define CAP    1024         // candidate capacity per batch
#define BPB    32           // blocks per batch for the scan pass
#define BS     256
#define TLOGIT 3.4f         // fast-path collect threshold (exp ~405/batch for N(0,1))

// monotonic uint key: key increasing <=> float increasing
__device__ __forceinline__ unsigned int mono_key(float x) {
    unsigned int u = __float_as_uint(x);
    return u ^ ((u >> 31) ? 0xFFFFFFFFu : 0x80000000u);
}
__device__ __forceinline__ float key_to_float(unsigned int k) {
    unsigned int u = (k & 0x80000000u) ? (k ^ 0x80000000u) : ~k;
    return __uint_as_float(u);
}

// Tiny init: only the per-batch fast-path counters need zeroing.
__global__ void pp_zero(unsigned int* __restrict__ cnt) {
    if (threadIdx.x < NBATCH) cnt[threadIdx.x] = 0u;
}

// Single full read of logits; collect candidates >= fixed logit threshold.
// Expected ~405 candidates/batch; valid iff K <= cnt <= CAP.
__global__ void __launch_bounds__(BS) pp_pass1(const float* __restrict__ logits,
                                               unsigned int* __restrict__ cnt,
                                               uint2* __restrict__ cand) {
    int b   = blockIdx.x / BPB;
    int sub = blockIdx.x % BPB;
    const float4* src = (const float4*)(logits + (size_t)b * QC);
    uint2* cb = cand + (size_t)b * CAP;
    for (int i = sub * BS + threadIdx.x; i < QC4; i += BPB * BS) {
        float4 v = src[i];
        // common path: one branch per 16B instead of four
        float m = fmaxf(fmaxf(v.x, v.y), fmaxf(v.z, v.w));
        if (m >= TLOGIT) {
            unsigned int base = 4u * (unsigned int)i;
            if (v.x >= TLOGIT) { unsigned int s = atomicAdd(&cnt[b], 1u); if (s < CAP) cb[s] = make_uint2(mono_key(v.x), base + 0u); }
            if (v.y >= TLOGIT) { unsigned int s = atomicAdd(&cnt[b], 1u); if (s < CAP) cb[s] = make_uint2(mono_key(v.y), base + 1u); }
            if (v.z >= TLOGIT) { unsigned int s = atomicAdd(&cnt[b], 1u); if (s < CAP) cb[s] = make_uint2(mono_key(v.z), base + 2u); }
            if (v.w >= TLOGIT) { unsigned int s = atomicAdd(&cnt[b], 1u); if (s < CAP) cb[s] = make_uint2(mono_key(v.w), base + 3u); }
        }
    }
}

// One block per batch. Fast path: rank candidates, write outputs.
// Fallback (statistically never taken, kept for exactness): block-local
// histogram select over the batch's logits, then collect + rank.
__global__ void __launch_bounds__(BS) pp_finish(const unsigned int* __restrict__ cnt,
                                                const uint2* __restrict__ cand,
                                                const float* __restrict__ logits,
                                                const float* __restrict__ bbox,
                                                const float* __restrict__ tsizes,
                                                float* __restrict__ out) {
    __shared__ uint2 sc[CAP];
    __shared__ unsigned int lh[NBINS];
    __shared__ unsigned int sn;
    __shared__ unsigned int tk_s;

    int b = blockIdx.x;
    unsigned int n = cnt[b];

    if (n >= (unsigned int)K && n <= (unsigned int)CAP) {
        // ---- fast path ----
        const uint2* cb = cand + (size_t)b * CAP;
        for (unsigned int i = threadIdx.x; i < n; i += BS) sc[i] = cb[i];
        __syncthreads();
    } else {
        // ---- exact fallback: block-local histogram over this batch ----
        for (int i = threadIdx.x; i < NBINS; i += BS) lh[i] = 0u;
        __syncthreads();
        const float4* src = (const float4*)(logits + (size_t)b * QC);
        for (int i = threadIdx.x; i < QC4; i += BS) {
            float4 v = src[i];
            atomicAdd(&lh[mono_key(v.x) >> 21], 1u);
            atomicAdd(&lh[mono_key(v.y) >> 21], 1u);
            atomicAdd(&lh[mono_key(v.z) >> 21], 1u);
            atomicAdd(&lh[mono_key(v.w) >> 21], 1u);
        }
        __syncthreads();
        if (threadIdx.x == 0) {
            unsigned int cum = 0;
            int tb = 0;
            for (int i = NBINS - 1; i >= 0; --i) {
                cum += lh[i];
                if (cum >= (unsigned int)K) { tb = i; break; }
            }
            tk_s = ((unsigned int)tb) << 21;
            sn = 0u;
        }
        __syncthreads();
        unsigned int tk = tk_s;
        for (int i = threadIdx.x; i < QC4; i += BS) {
            float4 v = src[i];
            unsigned int base = 4u * (unsigned int)i;
            unsigned int k0 = mono_key(v.x);
            unsigned int k1 = mono_key(v.y);
            unsigned int k2 = mono_key(v.z);
            unsigned int k3 = mono_key(v.w);
            if (k0 >= tk) { unsigned int s = atomicAdd(&sn, 1u); if (s < CAP) sc[s] = make_uint2(k0, base + 0u); }
            if (k1 >= tk) { unsigned int s = atomicAdd(&sn, 1u); if (s < CAP) sc[s] = make_uint2(k1, base + 1u); }
            if (k2 >= tk) { unsigned int s = atomicAdd(&sn, 1u); if (s < CAP) sc[s] = make_uint2(k2, base + 2u); }
            if (k3 >= tk) { unsigned int s = atomicAdd(&sn, 1u); if (s < CAP) sc[s] = make_uint2(k3, base + 3u); }
        }
        __syncthreads();
        n = sn;
        if (n > CAP) n = CAP;
    }

    // ---- exact top-K among candidates: rank by (key desc, idx asc) ----
    float img_h = tsizes[2 * b + 0];
    float img_w = tsizes[2 * b + 1];
    float* scores = out;
    float* labels = out + NBATCH * K;
    float* boxes  = out + 2 * NBATCH * K;
    for (unsigned int i = threadIdx.x; i < n; i += BS) {
        uint2 me = sc[i];
        int rank = 0;
        for (unsigned int j = 0; j < n; ++j) {
            uint2 o = sc[j];
            if (o.x > me.x || (o.x == me.x && o.y < me.y)) rank++;
        }
        if (rank < K) {
            float v = key_to_float(me.x);
            double sd = 1.0 / (1.0 + exp(-(double)v));
            scores[b * K + rank] = (float)sd;
            unsigned int idx = me.y;
            unsigned int q   = idx / C;
            unsigned int lab = idx - q * C;
            labels[b * K + rank] = (float)lab;
            const float* bb = bbox + ((size_t)b * Q + q) * 4;
            float cx = bb[0], cy = bb[1], w = bb[2], h = bb[3];
            float* o = boxes + ((size_t)b * K + (size_t)rank) * 4;
            o[0] = (cx - 0.5f * w) * img_w;
            o[1] = (cy - 0.5f * h) * img_h;
            o[2] = (cx + 0.5f * w) * img_w;
            o[3] = (cy + 0.5f * h) * img_h;
        }
    }
}

extern "C" void kernel_launch(void* const* d_in, const int* in_sizes, int n_in,
                              void* d_out, int out_size, void* d_ws, size_t ws_size,
                              hipStream_t stream) {
    const float* logits = (const float*)d_in[0];   // 64*1000*1203
    const float* bbox   = (const float*)d_in[1];   // 64*1000*4
    const float* tsizes = (const float*)d_in[2];   // 64*2
    float* out = (float*)d_out;

    char* ws = (char*)d_ws;
    unsigned int* cnt  = (unsigned int*)(ws);          // 256 B
    uint2*        cand = (uint2*)(ws + 1024);          // 512 KiB

    pp_zero<<<1, 64, 0, stream>>>(cnt);
    pp_pass1<<<NBATCH * BPB, BS, 0, stream>>>(logits, cnt, cand);
    pp_finish<<<NBATCH, BS, 0, stream>>>(cnt, cand, logits, bbox, tsizes, out);
}